// Round 7
// baseline (833.466 us; speedup 1.0000x reference)
//
#include <hip/hip_runtime.h>
#include <hip/hip_fp16.h>
#include <cstddef>
#include <cstdint>

#define N_NODES   100000
#define N_EDGES   1600000
#define N_GRAPHS  512
#define HIDDEN    128
#define N_LAYERS  3

#define SCAN_BS   1024
#define SCAN_NB   ((N_NODES + SCAN_BS - 1) / SCAN_BS)   // 98

// 8 dst-range slots (XCD affinity heuristic, R4-confirmed), 12500 nodes each
#define NPX        (N_NODES / 8)
#define BIN_BLOCKS 512
#define BIN_CHUNK  (N_EDGES / BIN_BLOCKS)   // 3125 exactly
#define DS_STRIPES 64                       // deg/scatter blocks per slot

typedef _Float16 half8 __attribute__((ext_vector_type(8)));
typedef float    float8 __attribute__((ext_vector_type(8)));
typedef float    floatx4 __attribute__((ext_vector_type(4)));

// ---------------------------------------------------------------------------
// Edge bucketing by dst-slot (deterministic, no global atomics).
// ---------------------------------------------------------------------------
__global__ __launch_bounds__(256) void bin_count_kernel(const int* __restrict__ dst,
                                                        int* __restrict__ counts) {
    const int e0 = blockIdx.x * BIN_CHUNK, e1 = e0 + BIN_CHUNK;
    int c0=0,c1=0,c2=0,c3=0,c4=0,c5=0,c6=0,c7=0;
    for (int e = e0 + threadIdx.x; e < e1; e += 256) {
        int s = dst[e] / NPX;
        c0 += (s==0); c1 += (s==1); c2 += (s==2); c3 += (s==3);
        c4 += (s==4); c5 += (s==5); c6 += (s==6); c7 += (s==7);
    }
    __shared__ int cs[8];
    if (threadIdx.x < 8) cs[threadIdx.x] = 0;
    __syncthreads();
    atomicAdd(&cs[0], c0); atomicAdd(&cs[1], c1);
    atomicAdd(&cs[2], c2); atomicAdd(&cs[3], c3);
    atomicAdd(&cs[4], c4); atomicAdd(&cs[5], c5);
    atomicAdd(&cs[6], c6); atomicAdd(&cs[7], c7);
    __syncthreads();
    if (threadIdx.x < 8) counts[blockIdx.x * 8 + threadIdx.x] = cs[threadIdx.x];
}

// one block, 512 threads: offsets[b][s] = slotbase[s] + prefix_b(counts[.][s])
__global__ __launch_bounds__(512) void bin_scan_kernel(const int* __restrict__ counts,
                                                       int* __restrict__ offsets,
                                                       int* __restrict__ slotbase) {
    __shared__ int tmp[512];
    __shared__ int totpost;
    const int t = threadIdx.x;
    int base = 0;
    for (int s = 0; s < 8; ++s) {
        tmp[t] = counts[t * 8 + s];
        __syncthreads();
        for (int off = 1; off < 512; off <<= 1) {
            int u = (t >= off) ? tmp[t - off] : 0;
            __syncthreads();
            tmp[t] += u;
            __syncthreads();
        }
        int excl = (t == 0) ? 0 : tmp[t - 1];
        offsets[t * 8 + s] = base + excl;
        if (t == 511) totpost = tmp[511];
        if (t == 0) slotbase[s] = base;
        __syncthreads();
        base += totpost;
        __syncthreads();
    }
    if (t == 0) slotbase[8] = base;   // == N_EDGES
}

__global__ __launch_bounds__(256) void bin_place_kernel(const int* __restrict__ src,
                                                        const int* __restrict__ dst,
                                                        const int* __restrict__ offsets,
                                                        int* __restrict__ bdst,
                                                        int* __restrict__ bsrc) {
    __shared__ int off[8];
    if (threadIdx.x < 8) off[threadIdx.x] = offsets[blockIdx.x * 8 + threadIdx.x];
    __syncthreads();
    const int e0 = blockIdx.x * BIN_CHUNK, e1 = e0 + BIN_CHUNK;
    for (int e = e0 + threadIdx.x; e < e1; e += 256) {
        int d = dst[e];
        int s = d / NPX;
        int p = atomicAdd(&off[s], 1);
        bdst[p] = d;
        bsrc[p] = src[e];
    }
}

// ---------------------------------------------------------------------------
// deg/scatter stream ONLY their slot's bucket; atomic targets XCD-local.
// grid = 8 slots x DS_STRIPES, slot = blockIdx&7.
// ---------------------------------------------------------------------------
__global__ __launch_bounds__(256) void deg_kernel(const int* __restrict__ bdst,
                                                  const int* __restrict__ slotbase,
                                                  int* __restrict__ deg) {
    const int s = blockIdx.x & 7, stripe = blockIdx.x >> 3;
    const int b0 = slotbase[s], b1 = slotbase[s + 1];
    const int cnt = b1 - b0;
    const int per = (cnt + DS_STRIPES - 1) / DS_STRIPES;
    const int e0 = b0 + stripe * per;
    int e1 = e0 + per; if (e1 > b1) e1 = b1;
    for (int e = e0 + threadIdx.x; e < e1; e += 256)
        atomicAdd(&deg[bdst[e]], 1);
}

__global__ __launch_bounds__(256) void scatter_kernel(const int* __restrict__ bdst,
                                                      const int* __restrict__ bsrc,
                                                      const int* __restrict__ slotbase,
                                                      int* __restrict__ pos,
                                                      int* __restrict__ csr_src) {
    const int s = blockIdx.x & 7, stripe = blockIdx.x >> 3;
    const int b0 = slotbase[s], b1 = slotbase[s + 1];
    const int cnt = b1 - b0;
    const int per = (cnt + DS_STRIPES - 1) / DS_STRIPES;
    const int e0 = b0 + stripe * per;
    int e1 = e0 + per; if (e1 > b1) e1 = b1;
    for (int e = e0 + threadIdx.x; e < e1; e += 256) {
        int d = bdst[e];
        int p = atomicAdd(&pos[d], 1);
        csr_src[p] = bsrc[e];
    }
}

// ---------------------------------------------------------------------------
// node-degree hierarchical scan (R2-confirmed)
// ---------------------------------------------------------------------------
__global__ __launch_bounds__(SCAN_BS) void scan_blocks_kernel(const int* __restrict__ deg,
                                                              int* __restrict__ scanned,
                                                              int* __restrict__ bsums) {
    __shared__ int tmp[SCAN_BS];
    const int t = threadIdx.x;
    const int i = blockIdx.x * SCAN_BS + t;
    int v = (i < N_NODES) ? deg[i] : 0;
    tmp[t] = v;
    __syncthreads();
#pragma unroll
    for (int off = 1; off < SCAN_BS; off <<= 1) {
        int u = (t >= off) ? tmp[t - off] : 0;
        __syncthreads();
        tmp[t] += u;
        __syncthreads();
    }
    if (i < N_NODES) scanned[i] = tmp[t];
    if (t == SCAN_BS - 1) bsums[blockIdx.x] = tmp[t];
}

__global__ __launch_bounds__(128) void scan_tops_kernel(int* __restrict__ bsums) {
    __shared__ int tmp[128];
    const int t = threadIdx.x;
    tmp[t] = (t < SCAN_NB) ? bsums[t] : 0;
    __syncthreads();
#pragma unroll
    for (int off = 1; off < 128; off <<= 1) {
        int u = (t >= off) ? tmp[t - off] : 0;
        __syncthreads();
        tmp[t] += u;
        __syncthreads();
    }
    if (t < SCAN_NB) bsums[t] = tmp[t];
}

__global__ __launch_bounds__(SCAN_BS) void scan_finalize_kernel(const int* __restrict__ deg,
                                                                const int* __restrict__ scanned,
                                                                const int* __restrict__ bsums,
                                                                int* __restrict__ row_ptr,
                                                                int* __restrict__ posb) {
    const int b = blockIdx.x;
    const int i = b * SCAN_BS + threadIdx.x;
    if (i >= N_NODES) return;
    const int off = (b > 0) ? bsums[b - 1] : 0;
    const int inc = off + scanned[i];
    row_ptr[i + 1] = inc;
    posb[i] = inc - deg[i];
    if (i == 0) row_ptr[0] = 0;
}

// ---------------------------------------------------------------------------
// fp32 -> fp16 bulk convert of X
// ---------------------------------------------------------------------------
__global__ void f2h_kernel(const float* __restrict__ in, __half* __restrict__ out) {
    int t = blockIdx.x * blockDim.x + threadIdx.x;
    const int n8 = (N_NODES * HIDDEN) / 8;
    if (t >= n8) return;
    const float4* in4 = (const float4*)in;
    float4 a = in4[t * 2 + 0];
    float4 b = in4[t * 2 + 1];
    __half2* o2 = (__half2*)out;
    o2[t * 4 + 0] = __floats2half2_rn(a.x, a.y);
    o2[t * 4 + 1] = __floats2half2_rn(a.z, a.w);
    o2[t * 4 + 2] = __floats2half2_rn(b.x, b.y);
    o2[t * 4 + 3] = __floats2half2_rn(b.z, b.w);
}

// wt[l][n][k] = w[l][k][n]  fp16 transposed weights for MFMA B frags
__global__ void wconv_kernel(const float* __restrict__ w1, const float* __restrict__ w2,
                             __half* __restrict__ wt1, __half* __restrict__ wt2) {
    int t = blockIdx.x * blockDim.x + threadIdx.x;
    if (t >= N_LAYERS * HIDDEN * HIDDEN) return;
    int l = t / (HIDDEN * HIDDEN);
    int r = t - l * (HIDDEN * HIDDEN);
    int k = r / HIDDEN, n = r - k * HIDDEN;
    wt1[(size_t)l * HIDDEN * HIDDEN + n * HIDDEN + k] = __float2half(w1[t]);
    wt2[(size_t)l * HIDDEN * HIDDEN + n * HIDDEN + k] = __float2half(w2[t]);
}

// ---------------------------------------------------------------------------
// GIN aggregation, half8 loads: one wave-load = 4 neighbor rows (64 lanes x
// 16B = 4 x 256B rows). grp=lane>>4 owns neighbor k+grp; m=lane&15 owns cols
// 8m..8m+7. fp32 accumulate; shfl_xor(16,32) butterfly merges group partials.
// ---------------------------------------------------------------------------
__global__ void gather_kernel(const __half* __restrict__ Xh, __half* __restrict__ Zh,
                              const int* __restrict__ row_ptr,
                              const int* __restrict__ csr_src) {
    int wave = (blockIdx.x * blockDim.x + threadIdx.x) >> 6;
    int lane = threadIdx.x & 63;
    if (wave >= N_NODES) return;
    const int grp = lane >> 4;     // 0..3
    const int m   = lane & 15;     // 0..15
    const half8* H8 = (const half8*)Xh;   // row = 16 half8

    float8 acc = {0.f,0.f,0.f,0.f,0.f,0.f,0.f,0.f};
    int k = row_ptr[wave];
    const int end = row_ptr[wave + 1];

    for (; k + 8 <= end; k += 8) {
        int n0 = csr_src[k + grp];
        int n1 = csr_src[k + 4 + grp];
        half8 v0 = H8[(size_t)n0 * 16 + m];
        half8 v1 = H8[(size_t)n1 * 16 + m];
        acc += __builtin_convertvector(v0, float8);
        acc += __builtin_convertvector(v1, float8);
    }
    if (k + 4 <= end) {
        int n0 = csr_src[k + grp];
        half8 v0 = H8[(size_t)n0 * 16 + m];
        acc += __builtin_convertvector(v0, float8);
        k += 4;
    }
    int rem = end - k;             // 0..3
    if (grp < rem) {
        int n0 = csr_src[k + grp];
        half8 v0 = H8[(size_t)n0 * 16 + m];
        acc += __builtin_convertvector(v0, float8);
    }

    // butterfly across the 4 groups (lanes ^16, ^32)
#pragma unroll
    for (int j = 0; j < 8; ++j) acc[j] += __shfl_xor(acc[j], 16);
#pragma unroll
    for (int j = 0; j < 8; ++j) acc[j] += __shfl_xor(acc[j], 32);

    // self term (added once, post-butterfly; identical in all lanes)
    half8 sv = H8[(size_t)wave * 16 + m];
    acc += __builtin_convertvector(sv, float8);

    if (grp == 0) {
        half8 o = __builtin_convertvector(acc, half8);
        ((half8*)Zh)[(size_t)wave * 16 + m] = o;
    }
}

// ---------------------------------------------------------------------------
// MFMA GEMM (R6-verified layouts): C = relu(A @ W + bias), all fp16 io,
// fp32 accumulate. One wave = 16 rows x 128 cols; block = 4 waves.
// ---------------------------------------------------------------------------
__global__ __launch_bounds__(256) void mm16_kernel(const __half* __restrict__ A,
                                                   const __half* __restrict__ Wt,
                                                   const float* __restrict__ bias,
                                                   __half* __restrict__ C16, int M) {
    const int wave = threadIdx.x >> 6;
    const int lane = threadIdx.x & 63;
    const int m = lane & 15;
    const int q = lane >> 4;
    const int row0 = blockIdx.x * 64 + wave * 16;

    int ra = row0 + m; if (ra > M - 1) ra = M - 1;
    const half8* Arow = (const half8*)(A + (size_t)ra * HIDDEN);
    half8 a0 = Arow[q];
    half8 a1 = Arow[4 + q];
    half8 a2 = Arow[8 + q];
    half8 a3 = Arow[12 + q];

#pragma unroll
    for (int ct = 0; ct < 8; ++ct) {
        const int n = ct * 16 + m;
        const half8* Wrow = (const half8*)(Wt + (size_t)n * HIDDEN);
        floatx4 acc = {0.f, 0.f, 0.f, 0.f};
        acc = __builtin_amdgcn_mfma_f32_16x16x32_f16(a0, Wrow[q],      acc, 0, 0, 0);
        acc = __builtin_amdgcn_mfma_f32_16x16x32_f16(a1, Wrow[4 + q],  acc, 0, 0, 0);
        acc = __builtin_amdgcn_mfma_f32_16x16x32_f16(a2, Wrow[8 + q],  acc, 0, 0, 0);
        acc = __builtin_amdgcn_mfma_f32_16x16x32_f16(a3, Wrow[12 + q], acc, 0, 0, 0);
        const float b = bias[n];
#pragma unroll
        for (int r = 0; r < 4; ++r) {
            int row = row0 + q * 4 + r;
            if (row < M) {
                float v = fmaxf(acc[r] + b, 0.f);
                C16[(size_t)row * HIDDEN + n] = __float2half(v);
            }
        }
    }
}

// ---------------------------------------------------------------------------
// Global sum pooling per graph (batch sorted), fp16 in, fp32 accumulate.
// ---------------------------------------------------------------------------
#define POOL_CHUNK 128
__global__ void pool_kernel(const __half* __restrict__ Xh, const int* __restrict__ batch,
                            float* __restrict__ pooled, int layer) {
    const int f = threadIdx.x;
    int start = blockIdx.x * POOL_CHUNK;
    int end = start + POOL_CHUNK;
    if (end > N_NODES) end = N_NODES;
    float acc = 0.f;
    int gcur = batch[start];
    for (int n = start; n < end; ++n) {
        int g = batch[n];
        if (g != gcur) {
            atomicAdd(&pooled[(size_t)gcur * (HIDDEN * N_LAYERS) + layer * HIDDEN + f], acc);
            acc = 0.f;
            gcur = g;
        }
        acc += __half2float(Xh[(size_t)n * HIDDEN + f]);
    }
    atomicAdd(&pooled[(size_t)gcur * (HIDDEN * N_LAYERS) + layer * HIDDEN + f], acc);
}

// ---------------------------------------------------------------------------
// Classifier head (tiny, fp32)
// ---------------------------------------------------------------------------
__global__ __launch_bounds__(128) void cls_kernel(const float* __restrict__ pooled,
                                                  const float* __restrict__ w1,
                                                  const float* __restrict__ b1,
                                                  const float* __restrict__ w2,
                                                  const float* __restrict__ b2,
                                                  const float* __restrict__ w3,
                                                  const float* __restrict__ b3,
                                                  float* __restrict__ out) {
    __shared__ float hin[HIDDEN * N_LAYERS];
    __shared__ float h1[HIDDEN];
    __shared__ float red[HIDDEN];
    const int g = blockIdx.x;
    const int t = threadIdx.x;

    for (int i = t; i < HIDDEN * N_LAYERS; i += 128)
        hin[i] = pooled[(size_t)g * (HIDDEN * N_LAYERS) + i];
    __syncthreads();

    float s = 0.f;
    for (int k = 0; k < HIDDEN * N_LAYERS; ++k) s += hin[k] * w1[(size_t)k * HIDDEN + t];
    s = fmaxf(s + b1[t], 0.f);
    h1[t] = s;
    __syncthreads();

    float s2 = 0.f;
    for (int k = 0; k < HIDDEN; ++k) s2 += h1[k] * w2[(size_t)k * HIDDEN + t];
    s2 = fmaxf(s2 + b2[t], 0.f);

    red[t] = s2 * w3[t];
    __syncthreads();
    for (int off = 64; off > 0; off >>= 1) {
        if (t < off) red[t] += red[t + off];
        __syncthreads();
    }
    if (t == 0) out[g] = red[0] + b3[0];
}

// ---------------------------------------------------------------------------
extern "C" void kernel_launch(void* const* d_in, const int* in_sizes, int n_in,
                              void* d_out, int out_size, void* d_ws, size_t ws_size,
                              hipStream_t stream) {
    const float* X     = (const float*)d_in[0];
    const int*   ei    = (const int*)d_in[1];
    const int*   batch = (const int*)d_in[2];
    const float* w1all = (const float*)d_in[3];
    const float* b1all = (const float*)d_in[4];
    const float* w2all = (const float*)d_in[5];
    const float* b2all = (const float*)d_in[6];
    const float* cw1   = (const float*)d_in[7];
    const float* cb1   = (const float*)d_in[8];
    const float* cw2   = (const float*)d_in[9];
    const float* cb2   = (const float*)d_in[10];
    const float* cw3   = (const float*)d_in[11];
    const float* cb3   = (const float*)d_in[12];
    float* out = (float*)d_out;

    const int* src = ei;
    const int* dst = ei + N_EDGES;

    char* p = (char*)d_ws;
    auto alloc = [&](size_t bytes) {
        char* r = p;
        p += (bytes + 255) & ~(size_t)255;
        return r;
    };
    __half* hA      = (__half*)alloc((size_t)N_NODES * HIDDEN * sizeof(__half));
    __half* hB      = (__half*)alloc((size_t)N_NODES * HIDDEN * sizeof(__half));
    __half* zh      = (__half*)alloc((size_t)N_NODES * HIDDEN * sizeof(__half));
    __half* m1h     = (__half*)alloc((size_t)N_NODES * HIDDEN * sizeof(__half));
    __half* wt1     = (__half*)alloc((size_t)N_LAYERS * HIDDEN * HIDDEN * sizeof(__half));
    __half* wt2     = (__half*)alloc((size_t)N_LAYERS * HIDDEN * HIDDEN * sizeof(__half));
    int*    bdst    = (int*)alloc((size_t)N_EDGES * sizeof(int));
    int*    bsrc    = (int*)alloc((size_t)N_EDGES * sizeof(int));
    int*    csr     = (int*)alloc((size_t)N_EDGES * sizeof(int));
    int*    rowp    = (int*)alloc((size_t)(N_NODES + 1) * sizeof(int));
    int*    posb    = (int*)alloc((size_t)N_NODES * sizeof(int));
    int*    deg     = (int*)alloc((size_t)N_NODES * sizeof(int));
    int*    scanned = (int*)alloc((size_t)N_NODES * sizeof(int));
    int*    bsums   = (int*)alloc((size_t)SCAN_NB * sizeof(int));
    int*    counts  = (int*)alloc((size_t)BIN_BLOCKS * 8 * sizeof(int));
    int*    offsets = (int*)alloc((size_t)BIN_BLOCKS * 8 * sizeof(int));
    int*    slotbase= (int*)alloc(9 * sizeof(int));
    float*  pooled  = (float*)alloc((size_t)N_GRAPHS * HIDDEN * N_LAYERS * sizeof(float));

    hipMemsetAsync(deg, 0, (size_t)N_NODES * sizeof(int), stream);
    hipMemsetAsync(pooled, 0, (size_t)N_GRAPHS * HIDDEN * N_LAYERS * sizeof(float), stream);

    // CSR build: bucket edges by dst-slot, then slot-local deg/scan/scatter
    bin_count_kernel<<<BIN_BLOCKS, 256, 0, stream>>>(dst, counts);
    bin_scan_kernel<<<1, 512, 0, stream>>>(counts, offsets, slotbase);
    bin_place_kernel<<<BIN_BLOCKS, 256, 0, stream>>>(src, dst, offsets, bdst, bsrc);
    deg_kernel<<<8 * DS_STRIPES, 256, 0, stream>>>(bdst, slotbase, deg);
    scan_blocks_kernel<<<SCAN_NB, SCAN_BS, 0, stream>>>(deg, scanned, bsums);
    scan_tops_kernel<<<1, 128, 0, stream>>>(bsums);
    scan_finalize_kernel<<<SCAN_NB, SCAN_BS, 0, stream>>>(deg, scanned, bsums, rowp, posb);
    scatter_kernel<<<8 * DS_STRIPES, 256, 0, stream>>>(bdst, bsrc, slotbase, posb, csr);

    const int f2h_grid = ((N_NODES * HIDDEN / 8) + 255) / 256;
    f2h_kernel<<<f2h_grid, 256, 0, stream>>>(X, hA);
    wconv_kernel<<<(N_LAYERS * HIDDEN * HIDDEN + 255) / 256, 256, 0, stream>>>(w1all, w2all, wt1, wt2);

    const int mm_grid   = (N_NODES + 63) / 64;
    const int gat_grid  = (N_NODES + 3) / 4;
    const int pool_grid = (N_NODES + POOL_CHUNK - 1) / POOL_CHUNK;

    __half* hcur = hA;
    for (int l = 0; l < N_LAYERS; ++l) {
        __half* hnext = (l & 1) ? hA : hB;
        gather_kernel<<<gat_grid, 256, 0, stream>>>(hcur, zh, rowp, csr);
        mm16_kernel<<<mm_grid, 256, 0, stream>>>(zh,
                                                 wt1 + (size_t)l * HIDDEN * HIDDEN,
                                                 b1all + (size_t)l * HIDDEN,
                                                 m1h, N_NODES);
        mm16_kernel<<<mm_grid, 256, 0, stream>>>(m1h,
                                                 wt2 + (size_t)l * HIDDEN * HIDDEN,
                                                 b2all + (size_t)l * HIDDEN,
                                                 hnext, N_NODES);
        pool_kernel<<<pool_grid, POOL_CHUNK, 0, stream>>>(hnext, batch, pooled, l);
        hcur = hnext;
    }

    cls_kernel<<<N_GRAPHS, 128, 0, stream>>>(pooled, cw1, cb1, cw2, cb2, cw3, cb3, out);
}